// Round 12
// baseline (255.364 us; speedup 1.0000x reference)
//
#include <hip/hip_runtime.h>

#define NN 20000
#define COLS 40
#define CPAD 41

typedef _Float16 f16x2 __attribute__((ext_vector_type(2)));
typedef unsigned short u16x2 __attribute__((ext_vector_type(2)));

union U32H2 { unsigned int u; f16x2 h; };
union U32S2 { unsigned int u; u16x2 s; };

__device__ __forceinline__ f16x2 bc_h2(unsigned int u) { U32H2 x; x.u = u; return x.h; }
__device__ __forceinline__ unsigned int dup_h(float v) {
    _Float16 h = (_Float16)v;
    unsigned short b = __builtin_bit_cast(unsigned short, h);
    return ((unsigned int)b << 16) | b;
}
__device__ __forceinline__ unsigned int pkrtz_u32(float a, float b) {
    return __builtin_bit_cast(unsigned int, __builtin_amdgcn_cvt_pkrtz(a, b));
}
__device__ __forceinline__ u16x2 pkmax2(u16x2 a, u16x2 b) {
    return __builtin_elementwise_max(a, b);
}

// ---------------- prep: softmax(W) -> packed-f16 pi tables ----------------
__global__ __launch_bounds__(1024) void prep_kernel(const float* __restrict__ W,
                                                    unsigned int* __restrict__ pi_pk,
                                                    unsigned int* __restrict__ pi_t_pk,
                                                    unsigned int* __restrict__ pi1_pk,
                                                    unsigned int* __restrict__ pi2_pk) {
    __shared__ float red[1024];
    __shared__ float piL[4096];
    int t = threadIdx.x;
    float4 wv = ((const float4*)W)[t];
    float m = fmaxf(fmaxf(wv.x, wv.y), fmaxf(wv.z, wv.w));
    red[t] = m; __syncthreads();
    for (int s = 512; s > 0; s >>= 1) {
        if (t < s) red[t] = fmaxf(red[t], red[t + s]);
        __syncthreads();
    }
    m = red[0];
    __syncthreads();
    float e0 = expf(wv.x - m), e1 = expf(wv.y - m);
    float e2 = expf(wv.z - m), e3 = expf(wv.w - m);
    red[t] = e0 + e1 + e2 + e3;
    __syncthreads();
    for (int s = 512; s > 0; s >>= 1) {
        if (t < s) red[t] += red[t + s];
        __syncthreads();
    }
    float inv = 1.0f / red[0];
    float p[4] = { e0 * inv, e1 * inv, e2 * inv, e3 * inv };
#pragma unroll
    for (int i = 0; i < 4; i++) {
        int f = t * 4 + i;
        piL[f] = p[i];
        unsigned int d = dup_h(p[i]);
        pi_pk[f] = d;
        pi_t_pk[(f & 63) * 64 + (f >> 6)] = d;  // transposed [k][j]
    }
    __syncthreads();
    if (t < 64) {
        float s = 0.f;
        for (int k = 0; k < 64; k++) s += piL[t * 64 + k];
        pi1_pk[t] = dup_h(s);
    } else if (t < 128) {
        int k = t - 64;
        float s = 0.f;
        for (int j = 0; j < 64; j++) s += piL[j * 64 + k];
        pi2_pk[k] = dup_h(s);
    }
}

// ---------------- pack a0 fp32 (B,N) planes -> u8x4 table ----------------
__global__ __launch_bounds__(1024) void pack_kernel(const float* __restrict__ a0,
                                                    unsigned int* __restrict__ T0) {
    int i = blockIdx.x * 1024 + threadIdx.x;
    if (i < NN) {
        unsigned int b0 = __float2uint_rn(__saturatef(a0[i]) * 255.0f);
        unsigned int b1 = __float2uint_rn(__saturatef(a0[NN + i]) * 255.0f);
        unsigned int b2 = __float2uint_rn(__saturatef(a0[2 * NN + i]) * 255.0f);
        unsigned int b3 = __float2uint_rn(__saturatef(a0[3 * NN + i]) * 255.0f);
        T0[i] = b0 | (b1 << 8) | (b2 << 16) | (b3 << 24);
    }
}

// ---------------- phase 1: lane-per-(row, 5-col group) ----------------
// Thread t owns row = t>>3 (0..127) and cols (t&7)*5 + {0..4}. Per task it
// reads the full 64 B X line (4 x int4, coalesced), gathers 16 table words,
// and does the 8-way clause max IN-REGISTER (two packed-u16 chains, no DPP,
// no masked lanes). X loads double-buffered across tasks.
__device__ __forceinline__ void phase1(
    const unsigned int* __restrict__ tab,
    unsigned int (* __restrict__ Ftb)[2][CPAD],
    const int* __restrict__ Xp,   // X1 or X2, wave-uniform
    int rowk,                     // row & 63 (k within table)
    int row,                      // Ft row (0..127)
    int col0,                     // (t&7)*5
    int nb, int cn) {
    const float sc = 1.0f / 65025.0f;
    const char* Xb = (const char*)Xp;
    // byte offset of this row's (k) X block, per-lane
    unsigned int roff = (unsigned int)rowk * (unsigned int)(NN * 64);
    int4 xq[4];
    {
        int c = 0;
        int n = nb + (c < cn ? col0 + c : 0);
        const int4* p = (const int4*)(Xb + roff + (unsigned int)n * 64u);
        xq[0] = p[0]; xq[1] = p[1]; xq[2] = p[2]; xq[3] = p[3];
    }
#pragma unroll
    for (int tk = 0; tk < 5; ++tk) {
        int4 nx[4];
        if (tk < 4) {
            int c = tk + 1;
            int n = nb + (col0 + c < cn ? col0 + c : 0);
            const int4* p = (const int4*)(Xb + roff + (unsigned int)n * 64u);
            nx[0] = p[0]; nx[1] = p[1]; nx[2] = p[2]; nx[3] = p[3];
        }
        // 16 gathers
        unsigned int ga[8], gb[8];
#pragma unroll
        for (int i = 0; i < 4; ++i) {
            ga[2 * i]     = tab[xq[i].x];
            gb[2 * i]     = tab[xq[i].y];
            ga[2 * i + 1] = tab[xq[i].z];
            gb[2 * i + 1] = tab[xq[i].w];
        }
        // packed-u16 products, two chains: pe=(b0,b2), po=(b1,b3)
        u16x2 pe[8], po[8];
#pragma unroll
        for (int i = 0; i < 8; ++i) {
            U32S2 a, b;
            a.u = ga[i] & 0x00FF00FFu; b.u = gb[i] & 0x00FF00FFu;
            pe[i] = a.s * b.s;
            a.u = (ga[i] >> 8) & 0x00FF00FFu; b.u = (gb[i] >> 8) & 0x00FF00FFu;
            po[i] = a.s * b.s;
        }
        // in-register max tree over 8 w
        u16x2 e0 = pkmax2(pkmax2(pe[0], pe[1]), pkmax2(pe[2], pe[3]));
        u16x2 e1 = pkmax2(pkmax2(pe[4], pe[5]), pkmax2(pe[6], pe[7]));
        u16x2 o0 = pkmax2(pkmax2(po[0], po[1]), pkmax2(po[2], po[3]));
        u16x2 o1 = pkmax2(pkmax2(po[4], po[5]), pkmax2(po[6], po[7]));
        U32S2 peu, pou;
        peu.s = pkmax2(e0, e1);
        pou.s = pkmax2(o0, o1);
        int col = col0 + tk;
        if (col < cn) {
            float f0 = (float)(peu.u & 0xFFFFu) * sc;   // b0
            float f1 = (float)(pou.u & 0xFFFFu) * sc;   // b1
            float f2 = (float)(peu.u >> 16) * sc;       // b2
            float f3 = (float)(pou.u >> 16) * sc;       // b3
            Ftb[row][0][col] = pkrtz_u32(f0, f1);
            Ftb[row][1][col] = pkrtz_u32(f2, f3);
        }
        xq[0] = nx[0]; xq[1] = nx[1]; xq[2] = nx[2]; xq[3] = nx[3];
    }
}

// ---------------- phase 2: bilinear partials for (qu, bp, n_l) ----------------
__device__ __forceinline__ float2 phase2(
    const unsigned int (* __restrict__ Ftb)[2][CPAD],
    const unsigned int* __restrict__ pi_t_pk,
    const unsigned int* __restrict__ pi1_pk,
    const unsigned int* __restrict__ pi2_pk,
    int qu, int bp, int n_l) {
    f16x2 zero = {(_Float16)0, (_Float16)0};
    f16x2 f1v[8];
    f16x2 eu = zero;
#pragma unroll
    for (int jj = 0; jj < 8; ++jj) {
        f1v[jj] = bc_h2(Ftb[qu * 8 + jj][bp][n_l]);
        eu += bc_h2(pi1_pk[qu * 8 + jj]) * f1v[jj];  // s_load
    }
    f16x2 euv = zero, ev = zero;
#pragma unroll 8
    for (int k = 0; k < 64; ++k) {
        f16x2 f2 = bc_h2(Ftb[64 + k][bp][n_l]);
        const uint4* pt = (const uint4*)(pi_t_pk + k * 64 + qu * 8);
        uint4 w0 = pt[0], w1 = pt[1];  // scalar addr -> s_load_dwordx4
        f16x2 ts = bc_h2(w0.x) * f1v[0] + bc_h2(w0.y) * f1v[1] +
                   bc_h2(w0.z) * f1v[2] + bc_h2(w0.w) * f1v[3] +
                   bc_h2(w1.x) * f1v[4] + bc_h2(w1.y) * f1v[5] +
                   bc_h2(w1.z) * f1v[6] + bc_h2(w1.w) * f1v[7];
        euv += f2 * ts;
        if (qu == 0) ev += bc_h2(pi2_pk[k]) * f2;
    }
    float p0 = (float)eu[0] - (float)euv[0];
    float p1 = (float)eu[1] - (float)euv[1];
    if (qu == 0) { p0 += (float)ev[0]; p1 += (float)ev[1]; }
    return make_float2(p0, p1);
}

// ---------------- fused predicate_forward iteration ----------------
template <int ITER>
__global__ __launch_bounds__(1024, 4) void fused_iter(
    const unsigned int* __restrict__ Tsrc,
    const int* __restrict__ X1, const int* __restrict__ X2,
    const unsigned int* __restrict__ pi_t_pk,
    const unsigned int* __restrict__ pi1_pk,
    const unsigned int* __restrict__ pi2_pk,
    const float* __restrict__ a0,
    unsigned int* __restrict__ Tdst, float* __restrict__ outP) {
    __shared__ unsigned int tab[NN];            // 80,000 B
    __shared__ unsigned int Ft[128][2][CPAD];   // 41,984 B
    __shared__ float redp[8][64][4];            //  8,192 B  (total 130,176)

    const int t = threadIdx.x;
    for (int i = t; i < NN; i += 1024) tab[i] = Tsrc[i];

    const int bid = (int)blockIdx.x;
    const int bstart = bid < 32 ? bid * 79 : 32 * 79 + (bid - 32) * 78;
    const int bcnt = bid < 32 ? 79 : 78;
    const int c0 = (bcnt + 1) >> 1;  // 40 or 39

    // phase-1 mapping
    const int row = t >> 3, rowk = row & 63, col0 = (t & 7) * 5;
    const int tsel = __builtin_amdgcn_readfirstlane(t >> 9);  // wave-uniform
    const int* Xp = tsel ? X2 : X1;
    // phase-2 mapping
    const int q = t >> 7, bp = (t >> 6) & 1, n_l = t & 63;
    const int qu = __builtin_amdgcn_readfirstlane(q);

    __syncthreads();  // tab ready

    for (int ch = 0; ch < 2; ++ch) {
        const int nb = bstart + (ch ? c0 : 0);
        const int cn = ch ? (bcnt - c0) : c0;

        phase1(tab, Ft, Xp, rowk, row, col0, nb, cn);
        __syncthreads();

        if (n_l < cn) {
            float2 pp = phase2(Ft, pi_t_pk, pi1_pk, pi2_pk, qu, bp, n_l);
            *(float2*)&redp[q][n_l][bp * 2] = pp;
        }
        __syncthreads();

        // combine + soft-OR (redp safe: next write is after next barrier)
        if (t < cn) {
            int gn = nb + t;
            float d0 = 0.f, d1 = 0.f, d2 = 0.f, d3 = 0.f;
#pragma unroll
            for (int q8 = 0; q8 < 8; ++q8) {
                d0 += redp[q8][t][0];
                d1 += redp[q8][t][1];
                d2 += redp[q8][t][2];
                d3 += redp[q8][t][3];
            }
            float ap0, ap1, ap2, ap3;
            if (ITER == 1) {
                ap0 = a0[gn]; ap1 = a0[NN + gn];
                ap2 = a0[2 * NN + gn]; ap3 = a0[3 * NN + gn];
            } else {
                unsigned int tv = tab[gn];
                ap0 = (float)(tv & 255u) * (1.0f / 255.0f);
                ap1 = (float)((tv >> 8) & 255u) * (1.0f / 255.0f);
                ap2 = (float)((tv >> 16) & 255u) * (1.0f / 255.0f);
                ap3 = (float)(tv >> 24) * (1.0f / 255.0f);
            }
            float an0 = 1.0f - (1.0f - ap0) * (1.0f - d0);
            float an1 = 1.0f - (1.0f - ap1) * (1.0f - d1);
            float an2 = 1.0f - (1.0f - ap2) * (1.0f - d2);
            float an3 = 1.0f - (1.0f - ap3) * (1.0f - d3);
            if (ITER == 1) {
                unsigned int b0 = __float2uint_rn(__saturatef(an0) * 255.0f);
                unsigned int b1 = __float2uint_rn(__saturatef(an1) * 255.0f);
                unsigned int b2 = __float2uint_rn(__saturatef(an2) * 255.0f);
                unsigned int b3 = __float2uint_rn(__saturatef(an3) * 255.0f);
                Tdst[gn] = b0 | (b1 << 8) | (b2 << 16) | (b3 << 24);
            } else {
                outP[gn] = an0;
                outP[NN + gn] = an1;
                outP[2 * NN + gn] = an2;
                outP[3 * NN + gn] = an3;
            }
        }
    }
}

extern "C" void kernel_launch(void* const* d_in, const int* in_sizes, int n_in,
                              void* d_out, int out_size, void* d_ws, size_t ws_size,
                              hipStream_t stream) {
    const float* a0 = (const float*)d_in[0];
    const float* W = (const float*)d_in[1];
    const int* X1 = (const int*)d_in[2];   // int64 in ref -> int32 on device
    const int* X2 = (const int*)d_in[3];
    float* out = (float*)d_out;

    // ws: pi_pk @0 (16,384) | pi_t_pk @16,384 (16,384) | pi1_pk @32,768 (256)
    // | pi2_pk @33,024 (256) | T0 @33,280 (80,000) | T1 @113,280 (80,000)
    if (ws_size < (size_t)193280) return;  // R5 measured ws >= 20.8 MB
    unsigned int* pi_pk  = (unsigned int*)d_ws;
    unsigned int* pi_t   = (unsigned int*)((char*)d_ws + 16384);
    unsigned int* pi1_pk = (unsigned int*)((char*)d_ws + 32768);
    unsigned int* pi2_pk = (unsigned int*)((char*)d_ws + 33024);
    unsigned int* T0     = (unsigned int*)((char*)d_ws + 33280);
    unsigned int* T1     = (unsigned int*)((char*)d_ws + 113280);

    prep_kernel<<<1, 1024, 0, stream>>>(W, pi_pk, pi_t, pi1_pk, pi2_pk);
    pack_kernel<<<20, 1024, 0, stream>>>(a0, T0);
    fused_iter<1><<<256, 1024, 0, stream>>>(T0, X1, X2, pi_t, pi1_pk, pi2_pk,
                                            a0, T1, nullptr);
    fused_iter<2><<<256, 1024, 0, stream>>>(T1, X1, X2, pi_t, pi1_pk, pi2_pk,
                                            nullptr, nullptr, out);
}